// Round 8
// baseline (101.491 us; speedup 1.0000x reference)
//
#include <hip/hip_runtime.h>

// DistributedMemory forward:
//   inputs[b,:] = P[doc_ids[b],:] + sum_c W[context_ids[b,c],:]      [B,128]
//   out[b,s]    = dot(inputs[b,:], outputs[:, sample_ids[b,s]])      [B,S]
// B=16384, C=8, S=10, D=128, N_WORDS=100000, N_DOCS=1e6. All f32.
//
// R7 -> R8: binned serve rebuilt for balance + occupancy:
//  - work-queue (global atomic) chunk dispatch: perfect load balance
//    (R7: 53/1024 blocks served 4 chunks vs 3 -> 33% tail)
//  - single-buffer slab 16.9 KB + 2 barriers/chunk -> 8 blocks/CU
//    (R7: 33.8 KB double-buffer -> 4 blocks/CU); pipelining kept by
//    issuing next chunk's global loads into registers before serving
//  - queue pop issued before slab write; latency hides under barrier+serve

#define VEC_DIM 128
#define NW      100000
#define NW4     (NW / 4)         // 25000
#define CTX     8
#define NSAMP   10
#define WB      32               // words per chunk
#define NCHUNK  (NW / WB)        // 3125
#define CAP     256
#define TS      132              // slab row stride in floats (16B-aligned)
#define QGRID   2048             // 8 blocks/CU x 256 CU

// -------- AB: inputs build + sample binning -------------------------------
__global__ __launch_bounds__(256) void build_bin_kernel(
    const int* __restrict__ doc_ids,
    const int* __restrict__ context_ids,
    const int* __restrict__ sample_ids,
    const float* __restrict__ P,       // [N_DOCS,128]
    const float* __restrict__ W,       // [NW,128]
    float* __restrict__ inputs,        // [B,128]
    int* __restrict__ counts,          // [NCHUNK]
    int* __restrict__ list)            // [NCHUNK][CAP]
{
    const int t    = threadIdx.x;
    const int tsub = t & 31;
    const int b    = blockIdx.x * 8 + (t >> 5);

    const float4* __restrict__ P4 = (const float4*)P;
    const float4* __restrict__ W4 = (const float4*)W;

    float4 v = P4[doc_ids[b] * 32 + tsub];
    #pragma unroll
    for (int c = 0; c < CTX; ++c) {
        float4 w4 = W4[context_ids[b * CTX + c] * 32 + tsub];
        v.x += w4.x; v.y += w4.y; v.z += w4.z; v.w += w4.w;
    }
    ((float4*)inputs)[b * 32 + tsub] = v;

    // bin this block's 8 b's worth of samples (80)
    if (t < 8 * NSAMP) {
        const int p = blockIdx.x * 8 * NSAMP + t;      // < 163840 < 2^18
        const int w = sample_ids[p];
        const int c = w >> 5;                          // WB = 32
        const int slot = atomicAdd(&counts[c], 1);
        if (slot < CAP)
            list[c * CAP + slot] = ((w & (WB - 1)) << 18) | p;
    }
}

// -------- E: work-queue single-buffer slab serve --------------------------
__global__ __launch_bounds__(256, 8) void serve_kernel(
    const float* __restrict__ outs,     // [128, NW]
    const float* __restrict__ inputs,   // [B,128]
    const int* __restrict__ counts,
    const int* __restrict__ list,
    int* __restrict__ queue,            // work-queue counter
    float* __restrict__ out)            // [B*S]
{
    __shared__ float slab[WB * TS];     // 16,896 B -> 8 blocks/CU
    __shared__ int s_ci;
    const int t = threadIdx.x;
    const float4* __restrict__ outs4 = (const float4*)outs;
    const float4* __restrict__ in4   = (const float4*)inputs;

    // initial pop
    if (t == 0) s_ci = atomicAdd(queue, 1);
    __syncthreads();
    int ci = s_ci;
    if (ci >= NCHUNK) return;

    const int u  = t & 7;
    const int d0 = t >> 3;
    float4 r0 = outs4[(d0 +  0) * NW4 + ci * 8 + u];
    float4 r1 = outs4[(d0 + 32) * NW4 + ci * 8 + u];
    float4 r2 = outs4[(d0 + 64) * NW4 + ci * 8 + u];
    float4 r3 = outs4[(d0 + 96) * NW4 + ci * 8 + u];

    while (true) {
        // pop next chunk early; latency hides under write+barrier+serve
        if (t == 0) s_ci = atomicAdd(queue, 1);

        // write staged regs -> slab (transposed [w][d])
        #pragma unroll
        for (int j = 0; j < 4; ++j) {
            slab[(4*u + j) * TS + d0 +  0] = (&r0.x)[j];
            slab[(4*u + j) * TS + d0 + 32] = (&r1.x)[j];
            slab[(4*u + j) * TS + d0 + 64] = (&r2.x)[j];
            slab[(4*u + j) * TS + d0 + 96] = (&r3.x)[j];
        }
        __syncthreads();               // slab ready; s_ci visible

        const int cn = s_ci;
        if (cn < NCHUNK) {             // issue next loads; cover = serve
            r0 = outs4[(d0 +  0) * NW4 + cn * 8 + u];
            r1 = outs4[(d0 + 32) * NW4 + cn * 8 + u];
            r2 = outs4[(d0 + 64) * NW4 + cn * 8 + u];
            r3 = outs4[(d0 + 96) * NW4 + cn * 8 + u];
        }

        // serve chunk ci from slab
        const int cnt = min(counts[ci], CAP);
        const float4* sl4 = (const float4*)slab;     // row stride 33 f4
        const int seg = t & 3;
        for (int i0 = 0; i0 < cnt; i0 += 64) {
            const int i = i0 + (t >> 2);
            if (i < cnt) {
                const int e = list[ci * CAP + i];
                const int p = e & 0x3FFFF;
                const int j = e >> 18;
                const unsigned bb = (unsigned)p / NSAMP;
                float ax = 0.f, ay = 0.f, az = 0.f, aw = 0.f;
                #pragma unroll
                for (int k = 0; k < 8; ++k) {
                    float4 a = in4[bb * 32 + seg * 8 + k];  // L2/L3-hot row
                    float4 o = sl4[j * 33  + seg * 8 + k];
                    ax += a.x * o.x; ay += a.y * o.y;
                    az += a.z * o.z; aw += a.w * o.w;
                }
                float s = (ax + ay) + (az + aw);
                s += __shfl_xor(s, 1, 64);
                s += __shfl_xor(s, 2, 64);
                if (seg == 0) out[p] = s;
            }
        }

        if (cn >= NCHUNK) break;
        ci = cn;
        __syncthreads();               // serve done before next slab write
    }
}

// -------- fallback (tiny ws): direct strided gather ----------------------
__global__ __launch_bounds__(128) void dm_fwd_direct(
    const int* __restrict__ doc_ids,
    const int* __restrict__ context_ids,
    const int* __restrict__ sample_ids,
    const float* __restrict__ P,
    const float* __restrict__ W,
    const float* __restrict__ outs,
    float* __restrict__ out)
{
    const int b = blockIdx.x;
    const int d = threadIdx.x;
    const int lane = d & 63;
    const int wave = d >> 6;

    float v = P[(long)doc_ids[b] * VEC_DIM + d];
    #pragma unroll
    for (int c = 0; c < CTX; ++c)
        v += W[(long)context_ids[b * CTX + c] * VEC_DIM + d];

    __shared__ float partial[2 * NSAMP];
    #pragma unroll
    for (int s = 0; s < NSAMP; ++s) {
        const int w = sample_ids[b * NSAMP + s];
        float p = v * outs[(long)d * NW + w];
        #pragma unroll
        for (int off = 32; off > 0; off >>= 1)
            p += __shfl_down(p, off, 64);
        if (lane == 0) partial[wave * NSAMP + s] = p;
    }
    __syncthreads();
    if (d < NSAMP) out[b * NSAMP + d] = partial[d] + partial[NSAMP + d];
}

extern "C" void kernel_launch(void* const* d_in, const int* in_sizes, int n_in,
                              void* d_out, int out_size, void* d_ws, size_t ws_size,
                              hipStream_t stream) {
    const int*   doc_ids     = (const int*)d_in[0];
    const int*   context_ids = (const int*)d_in[1];
    const int*   sample_ids  = (const int*)d_in[2];
    const float* P           = (const float*)d_in[3];
    const float* W           = (const float*)d_in[4];
    const float* outs        = (const float*)d_in[5];
    float*       out         = (float*)d_out;

    const int B = in_sizes[0];          // 16384

    const size_t off_inputs = 0;
    const size_t sz_inputs  = (size_t)B * VEC_DIM * sizeof(float);   // 8.4 MB
    const size_t off_q      = off_inputs + sz_inputs;                // queue: 1 int
    const size_t off_counts = off_q + 256;                           // counts after
    const size_t sz_counts  = 65536;                                 // >= NCHUNK*4
    const size_t off_list   = off_counts + sz_counts;
    const size_t sz_list    = (size_t)NCHUNK * CAP * sizeof(int);    // 3.2 MB
    const size_t needed     = off_list + sz_list;

    if (ws_size >= needed && (B % 8) == 0) {
        float* inputs = (float*)((char*)d_ws + off_inputs);
        int*   queue  = (int*)  ((char*)d_ws + off_q);
        int*   counts = (int*)  ((char*)d_ws + off_counts);
        int*   list   = (int*)  ((char*)d_ws + off_list);

        // zero queue + counts in one memset (contiguous region)
        hipMemsetAsync((char*)d_ws + off_q, 0,
                       256 + NCHUNK * sizeof(int), stream);
        build_bin_kernel<<<B / 8, 256, 0, stream>>>(
            doc_ids, context_ids, sample_ids, P, W, inputs, counts, list);
        serve_kernel<<<QGRID, 256, 0, stream>>>(
            outs, inputs, counts, list, queue, out);
    } else {
        dm_fwd_direct<<<B, 128, 0, stream>>>(doc_ids, context_ids, sample_ids,
                                             P, W, outs, out);
    }
}

// Round 9
// 36.558 us; speedup vs baseline: 2.7761x; 2.7761x over previous
//
#include <hip/hip_runtime.h>
#include <hip/hip_fp16.h>

// DistributedMemory forward:
//   inputs[b,:] = P[doc_ids[b],:] + sum_c W[context_ids[b,c],:]      [B,128]
//   out[b,s]    = dot(inputs[b,:], outputs[:, sample_ids[b,s]])      [B,S]
// B=16384, C=8, S=10, D=128, N_WORDS=100000, N_DOCS=1e6. All f32.
//
// R8 -> R9: binned structure abandoned for good (4 attempts, never < 55 µs
// vs transpose structure's stable 43.3). Transpose structure is at its byte
// floor (264 MB @ ~6.1 TB/s), so cut bytes: outsT (a scratch tensor we
// control) is written in fp16 -> transpose write 51.2->25.6 MB, gather
// 84->42 MB, total ~197 MB. Accumulation stays f32; only the gathered
// multiplicand is rounded to fp16 (rel err ~5e-4).

#define VEC_DIM 128
#define NW      100000
#define NW4     (NW / 4)         // 25000
#define CTX     8
#define NSAMP   10
#define TWB     32               // words per transpose tile (NW % 32 == 0)
#define TS      132              // LDS row stride in floats (16B-aligned)

struct alignas(8) Half4 { __half2 a, b; };   // 4 halves = 8 B

// -------- transpose+convert: outs[128,NW] f32 -> outsT[NW,128] fp16 -------
__global__ __launch_bounds__(256) void transpose_h_kernel(
    const float* __restrict__ in,    // [128, NW]
    Half4* __restrict__ outT)        // [NW, 128] halves, as [NW*32] Half4
{
    __shared__ float tile[TWB * TS];    // [w][d], 16,896 B
    const int t  = threadIdx.x;
    const int w0 = blockIdx.x * TWB;

    const float4* __restrict__ in4 = (const float4*)in;
    // read: 128 dims x 8 f4 along words = 1024 f4, 4/thread, coalesced segs
    #pragma unroll
    for (int i = 0; i < 4; ++i) {
        const int f4i = i * 256 + t;
        const int d = f4i >> 3;             // 0..127
        const int u = f4i & 7;              // f4 slot along w
        float4 v = in4[d * NW4 + (w0 >> 2) + u];
        tile[(4 * u + 0) * TS + d] = v.x;
        tile[(4 * u + 1) * TS + d] = v.y;
        tile[(4 * u + 2) * TS + d] = v.z;
        tile[(4 * u + 3) * TS + d] = v.w;
    }
    __syncthreads();

    // write: 32 w-rows x 32 Half4 = 1024, 4/thread; 256 B contiguous per row
    #pragma unroll
    for (int i = 0; i < 4; ++i) {
        const int f4i = i * 256 + t;
        const int w = f4i >> 5;             // 0..31
        const int q = f4i & 31;             // Half4 slot along d
        const float* src = &tile[w * TS + 4 * q];
        Half4 hv;
        hv.a = __floats2half2_rn(src[0], src[1]);
        hv.b = __floats2half2_rn(src[2], src[3]);
        outT[(w0 + w) * 32 + q] = hv;
    }
}

// -------- fused: build inputs in registers + gather fp16 rows + dot -------
__global__ __launch_bounds__(256) void dm_fwd_kernel(
    const int* __restrict__ doc_ids,
    const int* __restrict__ context_ids,
    const int* __restrict__ sample_ids,
    const float* __restrict__ P,       // [N_DOCS, 128]
    const float* __restrict__ W,       // [NW, 128]
    const Half4* __restrict__ outsT,   // [NW, 128] fp16
    float* __restrict__ out)           // [B, S]
{
    const int t = threadIdx.x & 31;                      // lane in sub-group
    const int b = blockIdx.x * 8 + (threadIdx.x >> 5);   // batch element

    const float4* __restrict__ P4 = (const float4*)P;
    const float4* __restrict__ W4 = (const float4*)W;

    // all indices fit 32-bit
    float4 v = P4[doc_ids[b] * 32 + t];
    #pragma unroll
    for (int c = 0; c < CTX; ++c) {
        float4 w4 = W4[context_ids[b * CTX + c] * 32 + t];
        v.x += w4.x; v.y += w4.y; v.z += w4.z; v.w += w4.w;
    }

    int wids[NSAMP];
    #pragma unroll
    for (int s = 0; s < NSAMP; ++s) wids[s] = sample_ids[b * NSAMP + s];

    #pragma unroll
    for (int s = 0; s < NSAMP; ++s) {
        Half4 hv = outsT[wids[s] * 32 + t];              // 256 B contiguous row
        float2 f0 = __half22float2(hv.a);
        float2 f1 = __half22float2(hv.b);
        float p = v.x * f0.x + v.y * f0.y + v.z * f1.x + v.w * f1.y;
        #pragma unroll
        for (int off = 16; off > 0; off >>= 1)
            p += __shfl_down(p, off, 32);
        if (t == 0) out[b * NSAMP + s] = p;
    }
}

// -------- fallback (tiny ws): direct strided gather, pure f32 -------------
__global__ __launch_bounds__(128) void dm_fwd_direct(
    const int* __restrict__ doc_ids,
    const int* __restrict__ context_ids,
    const int* __restrict__ sample_ids,
    const float* __restrict__ P,
    const float* __restrict__ W,
    const float* __restrict__ outs,    // [128, NW]
    float* __restrict__ out)
{
    const int b = blockIdx.x;
    const int d = threadIdx.x;
    const int lane = d & 63;
    const int wave = d >> 6;

    float v = P[(long)doc_ids[b] * VEC_DIM + d];
    #pragma unroll
    for (int c = 0; c < CTX; ++c)
        v += W[(long)context_ids[b * CTX + c] * VEC_DIM + d];

    __shared__ float partial[2 * NSAMP];
    #pragma unroll
    for (int s = 0; s < NSAMP; ++s) {
        const int w = sample_ids[b * NSAMP + s];
        float p = v * outs[(long)d * NW + w];
        #pragma unroll
        for (int off = 32; off > 0; off >>= 1)
            p += __shfl_down(p, off, 64);
        if (lane == 0) partial[wave * NSAMP + s] = p;
    }
    __syncthreads();
    if (d < NSAMP) out[b * NSAMP + d] = partial[d] + partial[NSAMP + d];
}

extern "C" void kernel_launch(void* const* d_in, const int* in_sizes, int n_in,
                              void* d_out, int out_size, void* d_ws, size_t ws_size,
                              hipStream_t stream) {
    const int*   doc_ids     = (const int*)d_in[0];
    const int*   context_ids = (const int*)d_in[1];
    const int*   sample_ids  = (const int*)d_in[2];
    const float* P           = (const float*)d_in[3];
    const float* W           = (const float*)d_in[4];
    const float* outs        = (const float*)d_in[5];
    float*       out         = (float*)d_out;

    const int B = in_sizes[0];  // 16384
    const size_t needed = (size_t)NW * VEC_DIM * sizeof(__half);  // 25.6 MB

    if (ws_size >= needed && (B % 8) == 0) {
        Half4* outsT = (Half4*)d_ws;
        transpose_h_kernel<<<NW / TWB, 256, 0, stream>>>(outs, outsT);
        dm_fwd_kernel<<<B / 8, 256, 0, stream>>>(doc_ids, context_ids, sample_ids,
                                                 P, W, outsT, out);
    } else {
        dm_fwd_direct<<<B, 128, 0, stream>>>(doc_ids, context_ids, sample_ids,
                                             P, W, outs, out);
    }
}

// Round 10
// 35.631 us; speedup vs baseline: 2.8484x; 1.0260x over previous
//
#include <hip/hip_runtime.h>
#include <hip/hip_fp16.h>

// DistributedMemory forward:
//   inputs[b,:] = P[doc_ids[b],:] + sum_c W[context_ids[b,c],:]      [B,128]
//   out[b,s]    = dot(inputs[b,:], outputs[:, sample_ids[b,s]])      [B,S]
// B=16384, C=8, S=10, D=128, N_WORDS=100000, N_DOCS=1e6. All f32.
//
// R9 -> R10: structure kept (transpose->fp16 scratch + fused gather/dot;
// 196 MB requested ~ 33.5 µs floor). Last lever: gather-phase MLP — issue
// all 10 outsT row loads into registers before any reduction (was 1
// outstanding load per 32-lane group, serialized by the shfl chain).
// __launch_bounds__(256,8) pins VGPR <= 64 so occupancy stays 32 waves/CU.

#define VEC_DIM 128
#define NW      100000
#define NW4     (NW / 4)         // 25000
#define CTX     8
#define NSAMP   10
#define TWB     32               // words per transpose tile (NW % 32 == 0)
#define TS      132              // LDS row stride in floats (16B-aligned)

struct alignas(8) Half4 { __half2 a, b; };   // 4 halves = 8 B

// -------- transpose+convert: outs[128,NW] f32 -> outsT[NW,128] fp16 -------
__global__ __launch_bounds__(256) void transpose_h_kernel(
    const float* __restrict__ in,    // [128, NW]
    Half4* __restrict__ outT)        // [NW, 128] halves, as [NW*32] Half4
{
    __shared__ float tile[TWB * TS];    // [w][d], 16,896 B
    const int t  = threadIdx.x;
    const int w0 = blockIdx.x * TWB;

    const float4* __restrict__ in4 = (const float4*)in;
    // read: 128 dims x 8 f4 along words = 1024 f4, 4/thread, coalesced segs
    #pragma unroll
    for (int i = 0; i < 4; ++i) {
        const int f4i = i * 256 + t;
        const int d = f4i >> 3;             // 0..127
        const int u = f4i & 7;              // f4 slot along w
        float4 v = in4[d * NW4 + (w0 >> 2) + u];
        tile[(4 * u + 0) * TS + d] = v.x;
        tile[(4 * u + 1) * TS + d] = v.y;
        tile[(4 * u + 2) * TS + d] = v.z;
        tile[(4 * u + 3) * TS + d] = v.w;
    }
    __syncthreads();

    // write: 32 w-rows x 32 Half4 = 1024, 4/thread; 256 B contiguous per row
    #pragma unroll
    for (int i = 0; i < 4; ++i) {
        const int f4i = i * 256 + t;
        const int w = f4i >> 5;             // 0..31
        const int q = f4i & 31;             // Half4 slot along d
        const float* src = &tile[w * TS + 4 * q];
        Half4 hv;
        hv.a = __floats2half2_rn(src[0], src[1]);
        hv.b = __floats2half2_rn(src[2], src[3]);
        outT[(w0 + w) * 32 + q] = hv;
    }
}

// -------- fused: build inputs in registers + gather fp16 rows + dot -------
__global__ __launch_bounds__(256, 8) void dm_fwd_kernel(
    const int* __restrict__ doc_ids,
    const int* __restrict__ context_ids,
    const int* __restrict__ sample_ids,
    const float* __restrict__ P,       // [N_DOCS, 128]
    const float* __restrict__ W,       // [NW, 128]
    const Half4* __restrict__ outsT,   // [NW, 128] fp16
    float* __restrict__ out)           // [B, S]
{
    const int t = threadIdx.x & 31;                      // lane in sub-group
    const int b = blockIdx.x * 8 + (threadIdx.x >> 5);   // batch element

    const float4* __restrict__ P4 = (const float4*)P;
    const float4* __restrict__ W4 = (const float4*)W;

    // all indices fit 32-bit
    float4 v = P4[doc_ids[b] * 32 + t];
    #pragma unroll
    for (int c = 0; c < CTX; ++c) {
        float4 w4 = W4[context_ids[b * CTX + c] * 32 + t];
        v.x += w4.x; v.y += w4.y; v.z += w4.z; v.w += w4.w;
    }

    int wids[NSAMP];
    #pragma unroll
    for (int s = 0; s < NSAMP; ++s) wids[s] = sample_ids[b * NSAMP + s];

    // MLP: all 10 gathers in flight before any reduction (20 VGPRs)
    Half4 hv[NSAMP];
    #pragma unroll
    for (int s = 0; s < NSAMP; ++s)
        hv[s] = outsT[wids[s] * 32 + t];                 // 256 B contiguous

    #pragma unroll
    for (int s = 0; s < NSAMP; ++s) {
        float2 f0 = __half22float2(hv[s].a);
        float2 f1 = __half22float2(hv[s].b);
        float p = v.x * f0.x + v.y * f0.y + v.z * f1.x + v.w * f1.y;
        #pragma unroll
        for (int off = 16; off > 0; off >>= 1)
            p += __shfl_down(p, off, 32);
        if (t == 0) out[b * NSAMP + s] = p;
    }
}

// -------- fallback (tiny ws): direct strided gather, pure f32 -------------
__global__ __launch_bounds__(128) void dm_fwd_direct(
    const int* __restrict__ doc_ids,
    const int* __restrict__ context_ids,
    const int* __restrict__ sample_ids,
    const float* __restrict__ P,
    const float* __restrict__ W,
    const float* __restrict__ outs,    // [128, NW]
    float* __restrict__ out)
{
    const int b = blockIdx.x;
    const int d = threadIdx.x;
    const int lane = d & 63;
    const int wave = d >> 6;

    float v = P[(long)doc_ids[b] * VEC_DIM + d];
    #pragma unroll
    for (int c = 0; c < CTX; ++c)
        v += W[(long)context_ids[b * CTX + c] * VEC_DIM + d];

    __shared__ float partial[2 * NSAMP];
    #pragma unroll
    for (int s = 0; s < NSAMP; ++s) {
        const int w = sample_ids[b * NSAMP + s];
        float p = v * outs[(long)d * NW + w];
        #pragma unroll
        for (int off = 32; off > 0; off >>= 1)
            p += __shfl_down(p, off, 64);
        if (lane == 0) partial[wave * NSAMP + s] = p;
    }
    __syncthreads();
    if (d < NSAMP) out[b * NSAMP + d] = partial[d] + partial[NSAMP + d];
}

extern "C" void kernel_launch(void* const* d_in, const int* in_sizes, int n_in,
                              void* d_out, int out_size, void* d_ws, size_t ws_size,
                              hipStream_t stream) {
    const int*   doc_ids     = (const int*)d_in[0];
    const int*   context_ids = (const int*)d_in[1];
    const int*   sample_ids  = (const int*)d_in[2];
    const float* P           = (const float*)d_in[3];
    const float* W           = (const float*)d_in[4];
    const float* outs        = (const float*)d_in[5];
    float*       out         = (float*)d_out;

    const int B = in_sizes[0];  // 16384
    const size_t needed = (size_t)NW * VEC_DIM * sizeof(__half);  // 25.6 MB

    if (ws_size >= needed && (B % 8) == 0) {
        Half4* outsT = (Half4*)d_ws;
        transpose_h_kernel<<<NW / TWB, 256, 0, stream>>>(outs, outsT);
        dm_fwd_kernel<<<B / 8, 256, 0, stream>>>(doc_ids, context_ids, sample_ids,
                                                 P, W, outsT, out);
    } else {
        dm_fwd_direct<<<B, 128, 0, stream>>>(doc_ids, context_ids, sample_ids,
                                             P, W, outs, out);
    }
}